// Round 1
// baseline (708.018 us; speedup 1.0000x reference)
//
#include <hip/hip_runtime.h>
#include <cfloat>
#include <cmath>

// ---------------- workspace layout (floats) ----------------
#define WS_XR     0        // 16*512 = 8192   x_r = fast_attention(inputs, fa_r)
#define WS_UPDW   8192     // 48              sigmoid gate upd_w[b][i]
#define WS_READW  8240     // 48              tanh(max) read_w[b][i]
#define WS_PMAX   8288     // 3*16*79 = 3792  per-tile max partials
#define WS_PIDX   12080    // 3792 (ints)     per-tile argmax partials
#define WS_RNEW   15872    // 48*256 = 12288  gated r' rows
// total 28160 floats = 110 KB

constexpr int NTILES = 79;   // ceil(10000 / 128)

// ---------------- reductions (wave = 64) ----------------
__device__ __forceinline__ float wave_sum(float v) {
#pragma unroll
  for (int o = 32; o > 0; o >>= 1) v += __shfl_xor(v, o);
  return v;
}
__device__ __forceinline__ float wave_max(float v) {
#pragma unroll
  for (int o = 32; o > 0; o >>= 1) v = fmaxf(v, __shfl_xor(v, o));
  return v;
}
__device__ __forceinline__ float block_sum(float v, float* red) {
  int lane = threadIdx.x & 63, w = threadIdx.x >> 6, nw = blockDim.x >> 6;
  v = wave_sum(v);
  __syncthreads();                 // protect red from previous use
  if (lane == 0) red[w] = v;
  __syncthreads();
  float s = 0.f;
  for (int k = 0; k < nw; k++) s += red[k];
  return s;
}
__device__ __forceinline__ float block_max(float v, float* red) {
  int lane = threadIdx.x & 63, w = threadIdx.x >> 6, nw = blockDim.x >> 6;
  v = wave_max(v);
  __syncthreads();
  if (lane == 0) red[w] = v;
  __syncthreads();
  float s = -FLT_MAX;
  for (int k = 0; k < nw; k++) s = fmaxf(s, red[k]);
  return s;
}

// ---------------- K1: fa_r + fa_u + upd_w (block per batch row) ----------------
__global__ __launch_bounds__(512) void k_fa_in(
    const float* __restrict__ x,
    const float* __restrict__ w1r, const float* __restrict__ b1r,
    const float* __restrict__ w2r, const float* __restrict__ b2r,
    const float* __restrict__ w1u, const float* __restrict__ b1u,
    const float* __restrict__ w2u, const float* __restrict__ b2u,
    const float* __restrict__ Wuw, const float* __restrict__ buw,
    float* __restrict__ xr_out, float* __restrict__ updw_out) {
  __shared__ float xs[512], hs[512], red[16];
  int b = blockIdx.x, tid = threadIdx.x;
  xs[tid] = x[b * 512 + tid];
  __syncthreads();

  // ---- r path: x_r = x * (softmax(x@w1r+b1r) @ w2r + b2r)
  float t = b1r[tid];
#pragma unroll 8
  for (int c = 0; c < 512; c++) t = fmaf(xs[c], w1r[c * 512 + tid], t);
  float mx = block_max(t, red);
  float e = expf(t - mx);
  float s = block_sum(e, red);
  hs[tid] = e / s;
  __syncthreads();
  float y = b2r[tid];
#pragma unroll 8
  for (int c = 0; c < 512; c++) y = fmaf(hs[c], w2r[c * 512 + tid], y);
  xr_out[b * 512 + tid] = xs[tid] * y;

  // ---- u path (block_max's internal barrier makes hs overwrite safe)
  t = b1u[tid];
#pragma unroll 8
  for (int c = 0; c < 512; c++) t = fmaf(xs[c], w1u[c * 512 + tid], t);
  mx = block_max(t, red);
  e = expf(t - mx);
  s = block_sum(e, red);
  hs[tid] = e / s;
  __syncthreads();
  y = b2u[tid];
#pragma unroll 8
  for (int c = 0; c < 512; c++) y = fmaf(hs[c], w2u[c * 512 + tid], y);
  float xu = xs[tid] * y;

  // ---- upd_w[b][i] = sigmoid(dot(x_u, W_uw[:,i]) + b_uw[i])
  for (int i = 0; i < 3; i++) {
    float p = xu * Wuw[tid * 3 + i];
    float si = block_sum(p, red);
    if (tid == 0) updw_out[b * 3 + i] = 1.f / (1.f + expf(-(si + buw[i])));
  }
}

// ---------------- K2: read matmul + per-tile max/argmax partials ----------------
// grid (79, 3); block 512 = 8 waves; wave w handles batches 2w, 2w+1;
// lane owns 2 consecutive s-columns. tanh is monotonic -> argmax on pre-activation.
__global__ __launch_bounds__(512) void k_read(
    const float* __restrict__ W, const float* __restrict__ brd,
    const float* __restrict__ xr,
    float* __restrict__ pmax, int* __restrict__ pidx) {
  __shared__ __align__(16) float xs[16 * 512];
  int tid = threadIdx.x, lane = tid & 63, w = tid >> 6;
  int i = blockIdx.y, tile = blockIdx.x;
  {
    const float4* s4 = (const float4*)xr;
    float4* d4 = (float4*)xs;
    for (int t = tid; t < 2048; t += 512) d4[t] = s4[t];
  }
  __syncthreads();
  int b0 = w * 2, b1 = b0 + 1;
  int s0 = tile * 128 + lane * 2;
  int sC = (s0 > 9998) ? 9998 : s0;            // clamp tail, mask later
  const float* Wp = W + i * 10000 + sC;
  const float* xap = xs + b0 * 512;
  const float* xbp = xs + b1 * 512;
  float a00 = 0.f, a01 = 0.f, a10 = 0.f, a11 = 0.f;
#pragma unroll 2
  for (int c = 0; c < 512; c += 4) {
    float4 xa = *(const float4*)(xap + c);
    float4 xb = *(const float4*)(xbp + c);
    float2 w0 = *(const float2*)(Wp + (size_t)(c + 0) * 30000);
    float2 w1 = *(const float2*)(Wp + (size_t)(c + 1) * 30000);
    float2 w2 = *(const float2*)(Wp + (size_t)(c + 2) * 30000);
    float2 w3 = *(const float2*)(Wp + (size_t)(c + 3) * 30000);
    a00 = fmaf(xa.x, w0.x, a00); a01 = fmaf(xa.x, w0.y, a01);
    a10 = fmaf(xb.x, w0.x, a10); a11 = fmaf(xb.x, w0.y, a11);
    a00 = fmaf(xa.y, w1.x, a00); a01 = fmaf(xa.y, w1.y, a01);
    a10 = fmaf(xb.y, w1.x, a10); a11 = fmaf(xb.y, w1.y, a11);
    a00 = fmaf(xa.z, w2.x, a00); a01 = fmaf(xa.z, w2.y, a01);
    a10 = fmaf(xb.z, w2.x, a10); a11 = fmaf(xb.z, w2.y, a11);
    a00 = fmaf(xa.w, w3.x, a00); a01 = fmaf(xa.w, w3.y, a01);
    a10 = fmaf(xb.w, w3.x, a10); a11 = fmaf(xb.w, w3.y, a11);
  }
  float2 bb = *(const float2*)(brd + i * 10000 + sC);
  bool ok0 = (s0 < 10000), ok1 = (s0 + 1 < 10000);
  float v00 = a00 + bb.x, v01 = a01 + bb.y;
  float v10 = a10 + bb.x, v11 = a11 + bb.y;
  float bv0 = ok0 ? v00 : -FLT_MAX; int bi0 = s0;
  if (ok1 && v01 > bv0) { bv0 = v01; bi0 = s0 + 1; }
  float bv1 = ok0 ? v10 : -FLT_MAX; int bi1 = s0;
  if (ok1 && v11 > bv1) { bv1 = v11; bi1 = s0 + 1; }
  // wave argmax reduce; partner lane always has strictly higher s, so
  // strict '>' keeps the lower index on ties (numpy first-max semantics).
#pragma unroll
  for (int o = 32; o > 0; o >>= 1) {
    float ov = __shfl_down(bv0, o); int oi = __shfl_down(bi0, o);
    if (ov > bv0) { bv0 = ov; bi0 = oi; }
    ov = __shfl_down(bv1, o); oi = __shfl_down(bi1, o);
    if (ov > bv1) { bv1 = ov; bi1 = oi; }
  }
  if (lane == 0) {
    int base = (i * 16 + b0) * NTILES + tile;
    pmax[base] = bv0; pidx[base] = bi0;
    base = (i * 16 + b1) * NTILES + tile;
    pmax[base] = bv1; pidx[base] = bi1;
  }
}

// ---------------- K3: argmax finalize + gather + fa_um + W_um + gate ----------------
// block per (b,i) row — all 48 update rows are independent of m.
__global__ __launch_bounds__(768) void k_um(
    const float* __restrict__ mem, const float* __restrict__ x,
    const float* __restrict__ w1, const float* __restrict__ b1,
    const float* __restrict__ w2, const float* __restrict__ b2,
    const float* __restrict__ Wum, const float* __restrict__ bum,
    const float* __restrict__ pmax, const int* __restrict__ pidx,
    const float* __restrict__ updw, float* __restrict__ readw,
    float* __restrict__ rnew) {
  __shared__ float xcs[768], hs[768], xus[768], part[768], red[16];
  __shared__ int sidx;
  int bi = blockIdx.x;
  int b = bi / 3, i = bi % 3;
  int tid = threadIdx.x, lane = tid & 63, w = tid >> 6;

  // 1. reduce the 79 tile partials -> read_idx, read_w
  if (w == 0) {
    float bv = -FLT_MAX; int bix = 0;
    const float* pm = pmax + (i * 16 + b) * NTILES;
    const int* pi = pidx + (i * 16 + b) * NTILES;
    for (int t = lane; t < NTILES; t += 64) {
      float v = pm[t]; int ix = pi[t];
      if (v > bv || (v == bv && ix < bix)) { bv = v; bix = ix; }
    }
#pragma unroll
    for (int o = 32; o > 0; o >>= 1) {
      float ov = __shfl_down(bv, o); int oi = __shfl_down(bix, o);
      if (ov > bv || (ov == bv && oi < bix)) { bv = ov; bix = oi; }
    }
    if (lane == 0) { sidx = bix; readw[b * 3 + i] = tanhf(bv); }
  }
  __syncthreads();

  // 2. xc = concat(memory[b, idx], inputs[b])
  if (tid < 256) xcs[tid] = mem[((size_t)b * 10000 + sidx) * 256 + tid];
  else           xcs[tid] = x[b * 512 + (tid - 256)];
  __syncthreads();

  // 3. t = xc@w1 + b1 ; softmax
  float t = b1[tid];
#pragma unroll 8
  for (int c = 0; c < 768; c++) t = fmaf(xcs[c], w1[c * 768 + tid], t);
  float mx = block_max(t, red);
  float e = expf(t - mx);
  float s = block_sum(e, red);
  hs[tid] = e / s;
  __syncthreads();

  // 4. xu = xc * (h@w2 + b2)
  float y = b2[tid];
#pragma unroll 8
  for (int c = 0; c < 768; c++) y = fmaf(hs[c], w2[c * 768 + tid], y);
  xus[tid] = xcs[tid] * y;
  __syncthreads();

  // 5. upd = relu(xu@W_um + b_um); r' = u*upd + (1-u)*r   (3-way split-K)
  int jj = tid & 255, ph = tid >> 8;   // ph in 0..2
  float p = 0.f;
  int c0 = ph * 256;
#pragma unroll 8
  for (int cc = 0; cc < 256; cc++) { int c = c0 + cc; p = fmaf(xus[c], Wum[c * 256 + jj], p); }
  part[tid] = p;
  __syncthreads();
  if (tid < 256) {
    float sum = part[tid] + part[tid + 256] + part[tid + 512] + bum[tid];
    float upd = fmaxf(sum, 0.f);
    float u = updw[b * 3 + i];
    rnew[(b * 3 + i) * 256 + tid] = u * upd + (1.f - u) * xcs[tid];
  }
}

// ---------------- K4: sequential fa_am chain (3 iters) + tanh -> out ----------------
// block per batch row; m carried in LDS across iterations.
__global__ __launch_bounds__(512) void k_am(
    const float* __restrict__ w1, const float* __restrict__ b1,
    const float* __restrict__ w2, const float* __restrict__ b2,
    const float* __restrict__ Wam, const float* __restrict__ bam,
    const float* __restrict__ rnew, const float* __restrict__ readw,
    float* __restrict__ out) {
  __shared__ float xc[512], hs[512], xa[512], part[512], ms[256], red[16];
  int b = blockIdx.x, tid = threadIdx.x;
  if (tid < 256) ms[tid] = 0.f;
  __syncthreads();
  for (int i = 0; i < 3; i++) {
    if (tid < 256) xc[tid] = rnew[(b * 3 + i) * 256 + tid];
    else           xc[tid] = ms[tid - 256];
    __syncthreads();
    float t = b1[tid];
#pragma unroll 8
    for (int c = 0; c < 512; c++) t = fmaf(xc[c], w1[c * 512 + tid], t);
    float mx = block_max(t, red);
    float e = expf(t - mx);
    float s = block_sum(e, red);
    hs[tid] = e / s;
    __syncthreads();
    float y = b2[tid];
#pragma unroll 8
    for (int c = 0; c < 512; c++) y = fmaf(hs[c], w2[c * 512 + tid], y);
    xa[tid] = xc[tid] * y;
    __syncthreads();
    int jj = tid & 255, ph = tid >> 8;   // 2-way split-K
    float p = 0.f;
    int c0 = ph * 256;
#pragma unroll 8
    for (int cc = 0; cc < 256; cc++) { int c = c0 + cc; p = fmaf(xa[c], Wam[c * 256 + jj], p); }
    part[tid] = p;
    __syncthreads();
    if (tid < 256) {
      float sum = part[tid] + part[tid + 256] + bam[tid];
      ms[tid] = readw[b * 3 + i] * fmaxf(sum, 0.f);
    }
    __syncthreads();
  }
  if (tid < 256) out[b * 256 + tid] = tanhf(ms[tid]);
}

// ---------------- launch ----------------
extern "C" void kernel_launch(void* const* d_in, const int* in_sizes, int n_in,
                              void* d_out, int out_size, void* d_ws, size_t ws_size,
                              hipStream_t stream) {
  const float* x    = (const float*)d_in[0];
  const float* mem  = (const float*)d_in[1];
  const float* w1r  = (const float*)d_in[2];
  const float* b1r  = (const float*)d_in[3];
  const float* w2r  = (const float*)d_in[4];
  const float* b2r  = (const float*)d_in[5];
  const float* Wrd  = (const float*)d_in[6];
  const float* brd  = (const float*)d_in[7];
  const float* w1u  = (const float*)d_in[8];
  const float* b1u  = (const float*)d_in[9];
  const float* w2u  = (const float*)d_in[10];
  const float* b2u  = (const float*)d_in[11];
  const float* Wuw  = (const float*)d_in[12];
  const float* buw  = (const float*)d_in[13];
  const float* w1um = (const float*)d_in[14];
  const float* b1um = (const float*)d_in[15];
  const float* w2um = (const float*)d_in[16];
  const float* b2um = (const float*)d_in[17];
  const float* Wum  = (const float*)d_in[18];
  const float* bum  = (const float*)d_in[19];
  const float* w1am = (const float*)d_in[20];
  const float* b1am = (const float*)d_in[21];
  const float* w2am = (const float*)d_in[22];
  const float* b2am = (const float*)d_in[23];
  const float* Wam  = (const float*)d_in[24];
  const float* bam  = (const float*)d_in[25];

  float* ws   = (float*)d_ws;
  float* xr   = ws + WS_XR;
  float* updw = ws + WS_UPDW;
  float* rdw  = ws + WS_READW;
  float* pmax = ws + WS_PMAX;
  int*   pidx = (int*)(ws + WS_PIDX);
  float* rnew = ws + WS_RNEW;
  float* out  = (float*)d_out;

  k_fa_in<<<16, 512, 0, stream>>>(x, w1r, b1r, w2r, b2r, w1u, b1u, w2u, b2u,
                                  Wuw, buw, xr, updw);
  k_read<<<dim3(NTILES, 3), 512, 0, stream>>>(Wrd, brd, xr, pmax, pidx);
  k_um<<<48, 768, 0, stream>>>(mem, x, w1um, b1um, w2um, b2um, Wum, bum,
                               pmax, pidx, updw, rdw, rnew);
  k_am<<<16, 512, 0, stream>>>(w1am, b1am, w2am, b2am, Wam, bam, rnew, rdw, out);
}